// Round 21
// baseline (327.033 us; speedup 1.0000x reference)
//
#include <hip/hip_runtime.h>
#include <hip/hip_fp16.h>

#define N_NODES 100000
#define N_EDGES 1600000
#define N_GRAPHS 2048
#define NFEAT 78
#define DIM 32
#define NLAYERS 5
#define OUTD 128
#define BN_EPS 1e-5f
#define NPB 32                       // nodes per tile
#define NT (N_NODES / NPB)           // 3125 tiles
#define NB2 ((NT + 1) / 2)           // 1563 layer blocks (2 tiles, reflected)
#define NBUK 391                     // coarse buckets (256 nodes each)
#define BNODES 256                   // nodes per bucket
#define STRIDE 4608                  // slab per bucket (mean 4092, +8 sigma)
#define EPB 4096                     // edges per bfill block
#define NBLK ((N_EDGES + EPB - 1) / EPB)      // 391
#define NSLOT 16                     // partial-stats slots
#define PSTRIDE (NSLOT * 2 * DIM)    // 1024 floats
#define OSTR (BNODES + 1)            // per-bucket offs stride (257)
#define WIN 4096                     // degree-sort window (nodes)
#define NWIN ((N_NODES + WIN - 1) / WIN)      // 25

// fp16 helpers
__device__ __forceinline__ float2 up2(unsigned u) {
    __half2 h = *reinterpret_cast<__half2*>(&u);
    return __half22float2(h);
}
__device__ __forceinline__ unsigned pk2(float a, float b) {
    __half2 h = __floats2half2_rn(a, b);
    return *reinterpret_cast<unsigned*>(&h);
}

// ---- prep: blocks [0,NBLK) bucket fill; rest gemm1 (x @ W1_0 -> fp16) ----
__global__ __launch_bounds__(256) void prep_kernel(
    const int* __restrict__ ei, int* __restrict__ bcnt, int* __restrict__ bdata,
    const float* __restrict__ x, const float* __restrict__ W1_0,
    unsigned short* __restrict__ y)
{
    __shared__ int cur[NBUK];
    __shared__ int gbl[NBUK];
    __shared__ float Wl[NFEAT * DIM];   // 9.75 KB
    int tid = threadIdx.x;

    if (blockIdx.x < NBLK) {
        int base = blockIdx.x * EPB;
        for (int i = tid; i < NBUK; i += 256) cur[i] = 0;
        __syncthreads();

        int ew[16], eb[16];
        const int4* s4 = (const int4*)ei;
        const int4* d4 = (const int4*)(ei + N_EDGES);
#pragma unroll
        for (int c = 0; c < 4; ++c) {
            int eidx = base + c * 1024 + tid * 4;
            if (eidx < N_EDGES) {
                int4 sv = s4[eidx >> 2];
                int4 dv = d4[eidx >> 2];
                ew[c*4+0] = sv.x | ((dv.x & 255) << 17); eb[c*4+0] = dv.x >> 8;
                ew[c*4+1] = sv.y | ((dv.y & 255) << 17); eb[c*4+1] = dv.y >> 8;
                ew[c*4+2] = sv.z | ((dv.z & 255) << 17); eb[c*4+2] = dv.z >> 8;
                ew[c*4+3] = sv.w | ((dv.w & 255) << 17); eb[c*4+3] = dv.w >> 8;
            } else {
                eb[c*4+0] = eb[c*4+1] = eb[c*4+2] = eb[c*4+3] = -1;
                ew[c*4+0] = ew[c*4+1] = ew[c*4+2] = ew[c*4+3] = 0;
            }
        }
        int slot[16];
#pragma unroll
        for (int k = 0; k < 16; ++k)
            slot[k] = (eb[k] >= 0) ? atomicAdd(&cur[eb[k]], 1) : 0;
        __syncthreads();
        for (int b = tid; b < NBUK; b += 256) {
            int c = cur[b];
            gbl[b] = (c > 0) ? atomicAdd(&bcnt[b], c) : 0;
        }
        __syncthreads();
#pragma unroll
        for (int k = 0; k < 16; ++k) {
            int b = eb[k];
            if (b >= 0) {
                int pos = gbl[b] + slot[k];
                if (pos < STRIDE) bdata[b * STRIDE + pos] = ew[k];
            }
        }
    } else {
        for (int i = tid; i < NFEAT * DIM; i += 256) Wl[i] = W1_0[i];
        __syncthreads();
        int t = (blockIdx.x - NBLK) * 256 + tid;
        int row = t >> 3;
        int c0 = (t & 7) * 4;
        float a0 = 0.f, a1 = 0.f, a2 = 0.f, a3 = 0.f;
        const float* hr = x + (long)row * NFEAT;
        for (int k = 0; k < NFEAT; ++k) {
            float xv = hr[k];
            a0 = fmaf(xv, Wl[k * DIM + c0 + 0], a0);
            a1 = fmaf(xv, Wl[k * DIM + c0 + 1], a1);
            a2 = fmaf(xv, Wl[k * DIM + c0 + 2], a2);
            a3 = fmaf(xv, Wl[k * DIM + c0 + 3], a3);
        }
        ((uint2*)y)[(long)row * 8 + (t & 7)] = make_uint2(pk2(a0, a1), pk2(a2, a3));
    }
}

// ---- cfill2: per-bucket LDS counting sort -> flat CSR ----
__global__ __launch_bounds__(256) void cfill2_kernel(
    const int* __restrict__ bcnt, const int* __restrict__ bdata,
    int* __restrict__ edge_src, int* __restrict__ offsB,
    int* __restrict__ gcursor)
{
    __shared__ int sorted[STRIDE];          // 18.4 KB
    __shared__ int cnt[BNODES], off[BNODES], cur[BNODES];
    __shared__ int gbS;
    int b = blockIdx.x, tid = threadIdx.x;
    int n = min(bcnt[b], STRIDE);
    const int* slab = bdata + (long)b * STRIDE;

    if (tid == 0) gbS = atomicAdd(gcursor, n);
    if (tid < BNODES) cnt[tid] = 0;
    __syncthreads();
    int gb = gbS;
    for (int i = tid; i < n; i += 256)
        atomicAdd(&cnt[slab[i] >> 17], 1);
    __syncthreads();
    int t = tid;
    if (t < BNODES) off[t] = cnt[t];
    __syncthreads();
    for (int o = 1; o < BNODES; o <<= 1) {
        int a = (t >= o && t < BNODES) ? off[t - o] : 0;
        __syncthreads();
        if (t < BNODES) off[t] += a;
        __syncthreads();
    }
    if (t < BNODES) {
        int excl = off[t] - cnt[t];
        off[t] = excl;
        cur[t] = excl;
        offsB[b * OSTR + t] = gb + excl;
    }
    if (tid == 0) offsB[b * OSTR + BNODES] = gb + n;
    __syncthreads();
    for (int i = tid; i < n; i += 256) {
        int w = slab[i];
        int pos = atomicAdd(&cur[w >> 17], 1);
        sorted[pos] = w & 0x1FFFF;
    }
    __syncthreads();
    for (int i = tid; i < n; i += 256)
        edge_src[gb + i] = sorted[i];
}

// ---- wsort: per-window degree sort -> perm + perm-ordered (ebase,deg)
//      metadata + old-beg; claims perm-ordered edge slots via ecursor ----
__global__ __launch_bounds__(256) void wsort_kernel(
    const int* __restrict__ offsB, int* __restrict__ perm,
    int2* __restrict__ pinfo, int* __restrict__ obeg,
    int* __restrict__ ecursor)
{
    __shared__ int hist[64], cur[64], dsum[64], dcur[64];
    __shared__ int ebaseS;
    int tid = threadIdx.x;
    int wbase = blockIdx.x * WIN;
    int wn = min(WIN, N_NODES - wbase);
    if (tid < 64) { hist[tid] = 0; dsum[tid] = 0; }
    __syncthreads();
    int bins[WIN / 256], degs[WIN / 256], obg[WIN / 256];
#pragma unroll
    for (int k = 0; k < WIN / 256; ++k) {
        int i = k * 256 + tid;
        int bin = -1, d = 0, ob = 0;
        if (i < wn) {
            int node = wbase + i;
            int o = (node >> 8) * OSTR + (node & 255);
            ob = offsB[o];
            d = offsB[o + 1] - ob;
            bin = min(d, 63);
            atomicAdd(&hist[bin], 1);
            atomicAdd(&dsum[bin], d);
        }
        bins[k] = bin; degs[k] = d; obg[k] = ob;
    }
    __syncthreads();
    if (tid < 64) {
        int v = hist[tid];
        int s = v;
        for (int off = 1; off < 64; off <<= 1) {
            int a = __shfl_up(s, off, 64);
            if ((tid & 63) >= off) s += a;
        }
        cur[tid] = s - v;
        int dv = dsum[tid];
        int ds = dv;
        for (int off = 1; off < 64; off <<= 1) {
            int a = __shfl_up(ds, off, 64);
            if ((tid & 63) >= off) ds += a;
        }
        dcur[tid] = ds - dv;
        if (tid == 63) ebaseS = atomicAdd(ecursor, ds);   // window edge total
    }
    __syncthreads();
    int eb = ebaseS;
#pragma unroll
    for (int k = 0; k < WIN / 256; ++k) {
        int bin = bins[k];
        if (bin >= 0) {
            int node = wbase + k * 256 + tid;
            int p = atomicAdd(&cur[bin], 1);
            int eo = atomicAdd(&dcur[bin], degs[k]);
            perm[wbase + p] = node;
            pinfo[wbase + p] = make_int2(eb + eo, degs[k]);
            obeg[wbase + p] = obg[k];
        }
    }
}

// ---- ecopy: re-pack edge runs into perm order (edge_new aliases bdata) ----
__global__ __launch_bounds__(256) void ecopy_kernel(
    const int2* __restrict__ pinfo, const int* __restrict__ obeg,
    const int* __restrict__ edge_src, int* __restrict__ edge_new)
{
    int i = blockIdx.x * 256 + threadIdx.x;
    if (i >= N_NODES) return;
    int2 bd = pinfo[i];
    int ob = obeg[i];
    for (int j = 0; j < bd.y; ++j)
        edge_new[bd.x + j] = edge_src[ob + j];
}

// ---- fused layer: 2 reflected-pair tiles per block; unroll-16 gather
//      (16 loads in flight vs 8 -> ~2x MLP).  Prologue (MM): BN-fold W1. ----
template<bool MM>
__global__ __launch_bounds__(256) void layer_kernel(
    const int* __restrict__ perm, const int2* __restrict__ pinfo,
    const int* __restrict__ edge_new,
    const unsigned short* __restrict__ zin,
    const float* __restrict__ W1g,          // unscaled W1 (MM only)
    const float* __restrict__ partial_prev, // prev stats (MM only)
    const float* __restrict__ gprev, const float* __restrict__ bprev,
    const float* __restrict__ b1v,
    const float* __restrict__ W2, const float* __restrict__ b2v,
    unsigned short* __restrict__ zout, float* __restrict__ partial)
{
    __shared__ float W1l[DIM * DIM];       // 4 KB (MM only)
    __shared__ float W2l[DIM * DIM];       // 4 KB
    __shared__ float zs[NPB][36];          // 4.5 KB; also prologue scratch
    __shared__ float b1l[DIM], b2l[DIM], cl[DIM];
    __shared__ float sscl[DIM], sshl[DIM];
    __shared__ float psum[DIM], psq[DIM];

    int tid = threadIdx.x;
    float* red = &zs[0][0];

    for (int i = tid; i < DIM * DIM; i += 256) W2l[i] = W2[i];
    if (tid < DIM) {
        b1l[tid] = b1v[tid]; b2l[tid] = b2v[tid];
        psum[tid] = 0.f; psq[tid] = 0.f;
    }
    if (MM) {
        int c = tid & 63, chunk = tid >> 6;
        float a = 0.f;
        for (int p = chunk; p < NSLOT; p += 4) a += partial_prev[p * 64 + c];
        red[tid] = a;
        __syncthreads();
        if (tid < 64) red[tid] = red[tid] + red[tid+64] + red[tid+128] + red[tid+192];
        __syncthreads();
        if (tid < DIM) {
            const float invN = 1.0f / (float)N_NODES;
            float S = red[tid], Q = red[tid + DIM];
            float mu = S * invN;
            float var = Q * invN - mu * mu;
            float sc = gprev[tid] * rsqrtf(var + BN_EPS);
            sscl[tid] = sc;
            sshl[tid] = bprev[tid] - mu * sc;
        }
        __syncthreads();
        for (int i = tid; i < DIM * DIM; i += 256) W1l[i] = sscl[i >> 5] * W1g[i];
        if (tid < DIM) {
            float cv = 0.f;
            for (int k = 0; k < DIM; ++k) cv = fmaf(sshl[k], W1g[k * DIM + tid], cv);
            cl[tid] = cv;
        }
    }
    __syncthreads();   // weights ready; zs scratch free

    int ln = tid >> 3, p = tid & 7;
    int c0 = p * 4;
    const uint2* zb = (const uint2*)zin;

#pragma unroll 1
    for (int tt = 0; tt < 2; ++tt) {
        int tile = tt ? (NT - 1 - (int)blockIdx.x) : (int)blockIdx.x;
        if (tt && tile <= (int)blockIdx.x) break;

        int idx = tile * NPB + ln;
        int node = perm[idx];
        int2 bd = pinfo[idx];            // broadcast load (8 lanes same addr)
        int beg = bd.x, deg = bd.y, end = beg + deg;

        // phase 1: gather (self + in-neighbors), unroll x16 then x8 then tail
        uint2 sv = zb[(long)node * 8 + p];
        float2 f;
        f = up2(sv.x); float a0 = f.x, a1 = f.y;
        f = up2(sv.y); float a2 = f.x, a3 = f.y;
        int e = beg;
        for (; e + 16 <= end; e += 16) {
            uint2 w0  = zb[(long)edge_new[e + 0]  * 8 + p];
            uint2 w1  = zb[(long)edge_new[e + 1]  * 8 + p];
            uint2 w2  = zb[(long)edge_new[e + 2]  * 8 + p];
            uint2 w3  = zb[(long)edge_new[e + 3]  * 8 + p];
            uint2 w4  = zb[(long)edge_new[e + 4]  * 8 + p];
            uint2 w5  = zb[(long)edge_new[e + 5]  * 8 + p];
            uint2 w6  = zb[(long)edge_new[e + 6]  * 8 + p];
            uint2 w7  = zb[(long)edge_new[e + 7]  * 8 + p];
            uint2 w8  = zb[(long)edge_new[e + 8]  * 8 + p];
            uint2 w9  = zb[(long)edge_new[e + 9]  * 8 + p];
            uint2 w10 = zb[(long)edge_new[e + 10] * 8 + p];
            uint2 w11 = zb[(long)edge_new[e + 11] * 8 + p];
            uint2 w12 = zb[(long)edge_new[e + 12] * 8 + p];
            uint2 w13 = zb[(long)edge_new[e + 13] * 8 + p];
            uint2 w14 = zb[(long)edge_new[e + 14] * 8 + p];
            uint2 w15 = zb[(long)edge_new[e + 15] * 8 + p];
            f = up2(w0.x);  a0 += f.x; a1 += f.y;  f = up2(w0.y);  a2 += f.x; a3 += f.y;
            f = up2(w1.x);  a0 += f.x; a1 += f.y;  f = up2(w1.y);  a2 += f.x; a3 += f.y;
            f = up2(w2.x);  a0 += f.x; a1 += f.y;  f = up2(w2.y);  a2 += f.x; a3 += f.y;
            f = up2(w3.x);  a0 += f.x; a1 += f.y;  f = up2(w3.y);  a2 += f.x; a3 += f.y;
            f = up2(w4.x);  a0 += f.x; a1 += f.y;  f = up2(w4.y);  a2 += f.x; a3 += f.y;
            f = up2(w5.x);  a0 += f.x; a1 += f.y;  f = up2(w5.y);  a2 += f.x; a3 += f.y;
            f = up2(w6.x);  a0 += f.x; a1 += f.y;  f = up2(w6.y);  a2 += f.x; a3 += f.y;
            f = up2(w7.x);  a0 += f.x; a1 += f.y;  f = up2(w7.y);  a2 += f.x; a3 += f.y;
            f = up2(w8.x);  a0 += f.x; a1 += f.y;  f = up2(w8.y);  a2 += f.x; a3 += f.y;
            f = up2(w9.x);  a0 += f.x; a1 += f.y;  f = up2(w9.y);  a2 += f.x; a3 += f.y;
            f = up2(w10.x); a0 += f.x; a1 += f.y;  f = up2(w10.y); a2 += f.x; a3 += f.y;
            f = up2(w11.x); a0 += f.x; a1 += f.y;  f = up2(w11.y); a2 += f.x; a3 += f.y;
            f = up2(w12.x); a0 += f.x; a1 += f.y;  f = up2(w12.y); a2 += f.x; a3 += f.y;
            f = up2(w13.x); a0 += f.x; a1 += f.y;  f = up2(w13.y); a2 += f.x; a3 += f.y;
            f = up2(w14.x); a0 += f.x; a1 += f.y;  f = up2(w14.y); a2 += f.x; a3 += f.y;
            f = up2(w15.x); a0 += f.x; a1 += f.y;  f = up2(w15.y); a2 += f.x; a3 += f.y;
        }
        for (; e + 8 <= end; e += 8) {
            uint2 v0 = zb[(long)edge_new[e + 0] * 8 + p];
            uint2 v1 = zb[(long)edge_new[e + 1] * 8 + p];
            uint2 v2 = zb[(long)edge_new[e + 2] * 8 + p];
            uint2 v3 = zb[(long)edge_new[e + 3] * 8 + p];
            uint2 v4 = zb[(long)edge_new[e + 4] * 8 + p];
            uint2 v5 = zb[(long)edge_new[e + 5] * 8 + p];
            uint2 v6 = zb[(long)edge_new[e + 6] * 8 + p];
            uint2 v7 = zb[(long)edge_new[e + 7] * 8 + p];
            f = up2(v0.x); a0 += f.x; a1 += f.y;  f = up2(v0.y); a2 += f.x; a3 += f.y;
            f = up2(v1.x); a0 += f.x; a1 += f.y;  f = up2(v1.y); a2 += f.x; a3 += f.y;
            f = up2(v2.x); a0 += f.x; a1 += f.y;  f = up2(v2.y); a2 += f.x; a3 += f.y;
            f = up2(v3.x); a0 += f.x; a1 += f.y;  f = up2(v3.y); a2 += f.x; a3 += f.y;
            f = up2(v4.x); a0 += f.x; a1 += f.y;  f = up2(v4.y); a2 += f.x; a3 += f.y;
            f = up2(v5.x); a0 += f.x; a1 += f.y;  f = up2(v5.y); a2 += f.x; a3 += f.y;
            f = up2(v6.x); a0 += f.x; a1 += f.y;  f = up2(v6.y); a2 += f.x; a3 += f.y;
            f = up2(v7.x); a0 += f.x; a1 += f.y;  f = up2(v7.y); a2 += f.x; a3 += f.y;
        }
        for (; e < end; ++e) {
            uint2 v = zb[(long)edge_new[e] * 8 + p];
            f = up2(v.x); a0 += f.x; a1 += f.y;
            f = up2(v.y); a2 += f.x; a3 += f.y;
        }
        *(float4*)&zs[ln][c0] = make_float4(a0, a1, a2, a3);
        // no barrier: zs row is wave-private (same-wave DS order)

        // phase 2: s = zsum@W1' + (deg+1)*c + b1 (or zsum + b1), relu; in-place
        float t4[4];
        if (MM) {
            t4[0] = t4[1] = t4[2] = t4[3] = 0.f;
#pragma unroll
            for (int k = 0; k < DIM; ++k) {
                float zk = zs[ln][k];
                t4[0] = fmaf(zk, W1l[k * DIM + c0 + 0], t4[0]);
                t4[1] = fmaf(zk, W1l[k * DIM + c0 + 1], t4[1]);
                t4[2] = fmaf(zk, W1l[k * DIM + c0 + 2], t4[2]);
                t4[3] = fmaf(zk, W1l[k * DIM + c0 + 3], t4[3]);
            }
            float dp1 = (float)(deg + 1);
#pragma unroll
            for (int j = 0; j < 4; ++j)
                t4[j] = fmaxf(fmaf(dp1, cl[c0 + j], t4[j]) + b1l[c0 + j], 0.f);
        } else {
            t4[0] = fmaxf(a0 + b1l[c0 + 0], 0.f);
            t4[1] = fmaxf(a1 + b1l[c0 + 1], 0.f);
            t4[2] = fmaxf(a2 + b1l[c0 + 2], 0.f);
            t4[3] = fmaxf(a3 + b1l[c0 + 3], 0.f);
        }
        *(float4*)&zs[ln][c0] = make_float4(t4[0], t4[1], t4[2], t4[3]);
        // lockstep wave: all k-loop reads above complete before this store

        // phase 3: z = relu(s@W2 + b2), fp16 write + stats
        float zv[4] = { b2l[c0 + 0], b2l[c0 + 1], b2l[c0 + 2], b2l[c0 + 3] };
#pragma unroll
        for (int k = 0; k < DIM; ++k) {
            float sk = zs[ln][k];
            zv[0] = fmaf(sk, W2l[k * DIM + c0 + 0], zv[0]);
            zv[1] = fmaf(sk, W2l[k * DIM + c0 + 1], zv[1]);
            zv[2] = fmaf(sk, W2l[k * DIM + c0 + 2], zv[2]);
            zv[3] = fmaf(sk, W2l[k * DIM + c0 + 3], zv[3]);
        }
#pragma unroll
        for (int j = 0; j < 4; ++j) zv[j] = fmaxf(zv[j], 0.f);
        ((uint2*)zout)[(long)node * 8 + p] =
            make_uint2(pk2(zv[0], zv[1]), pk2(zv[2], zv[3]));

        float sq[4];
#pragma unroll
        for (int j = 0; j < 4; ++j) sq[j] = zv[j] * zv[j];
#pragma unroll
        for (int off = 8; off < 64; off <<= 1) {
#pragma unroll
            for (int j = 0; j < 4; ++j) {
                zv[j] += __shfl_xor(zv[j], off, 64);
                sq[j] += __shfl_xor(sq[j], off, 64);
            }
        }
        if ((tid & 63) < 8) {
#pragma unroll
            for (int j = 0; j < 4; ++j) {
                atomicAdd(&psum[c0 + j], zv[j]);
                atomicAdd(&psq[c0 + j], sq[j]);
            }
        }
    }

    __syncthreads();
    if (tid < 2 * DIM) {
        float v = (tid < DIM) ? psum[tid] : psq[tid - DIM];
        atomicAdd(&partial[(blockIdx.x & (NSLOT - 1)) * 2 * DIM + tid], v);
    }
}

// ------- pool: RAW sums + per-graph node counts (no BN dependency) -------
__global__ __launch_bounds__(256) void pool_kernel(
    const unsigned short* __restrict__ z, const int* __restrict__ batch,
    float* __restrict__ praw, float* __restrict__ cntg)
{
    __shared__ float acc[32][32];
    __shared__ float cntL[32];
    __shared__ int slot[32];
    __shared__ int segg[32];
    __shared__ int nsegS;
    int tid = threadIdx.x;
    for (int i = tid; i < 1024; i += 256) ((float*)acc)[i] = 0.f;
    if (tid < 32) cntL[tid] = 0.f;
    int nodeBase = blockIdx.x * 32;
    if (tid < 32) {
        int nd = nodeBase + tid;
        int gv = batch[nd];
        int flag = (tid == 0) ? 1 : (gv != batch[nd - 1]);
        unsigned long long m = __ballot(flag);
        int s = __popcll(m & ((2ull << tid) - 1ull)) - 1;
        slot[tid] = s;
        if (flag) segg[s] = gv;
        if (tid == 0) nsegS = __popcll(m);
    }
    __syncthreads();

    int ln = tid >> 3;
    int p = tid & 7;
    long node = nodeBase + ln;
    uint2 u = ((const uint2*)z)[node * 8 + p];
    int c = p * 4;
    float2 f01 = up2(u.x), f23 = up2(u.y);
    int s = slot[ln];
    atomicAdd(&acc[s][c+0], f01.x);
    atomicAdd(&acc[s][c+1], f01.y);
    atomicAdd(&acc[s][c+2], f23.x);
    atomicAdd(&acc[s][c+3], f23.y);
    if (p == 0) atomicAdd(&cntL[s], 1.f);
    __syncthreads();

    int total = nsegS * 32;
    for (int i = tid; i < total; i += 256) {
        int r = i >> 5, dd = i & 31;
        float val = acc[r][dd];
        if (val != 0.f) atomicAdd(&praw[(long)segg[r] * DIM + dd], val);
    }
    if (tid < nsegS) atomicAdd(&cntg[segg[tid]], cntL[tid]);
}

// ---- fc: prologue computes layer-4 BN from partial4, then
//      out = relu(bfc + cnt*(shl@Wfc) + (scl.*praw)@Wfc) ----
__global__ __launch_bounds__(256) void fc_kernel(
    const float* __restrict__ praw, const float* __restrict__ cntg,
    const float* __restrict__ partial4,
    const float* __restrict__ g4, const float* __restrict__ be4,
    const float* __restrict__ Wfc, const float* __restrict__ bfc,
    float* __restrict__ out)
{
    __shared__ float Wl[DIM * OUTD];   // 16 KB
    __shared__ float red[256];
    __shared__ float sscl[DIM], sshl[DIM], dvec[OUTD];
    int tid = threadIdx.x;
    for (int i = tid; i < DIM * OUTD; i += 256) Wl[i] = Wfc[i];
    {
        int c = tid & 63, chunk = tid >> 6;
        float a = 0.f;
        for (int p = chunk; p < NSLOT; p += 4) a += partial4[p * 64 + c];
        red[tid] = a;
    }
    __syncthreads();
    if (tid < 64) red[tid] = red[tid] + red[tid+64] + red[tid+128] + red[tid+192];
    __syncthreads();
    if (tid < DIM) {
        const float invN = 1.0f / (float)N_NODES;
        float S = red[tid], Q = red[tid + DIM];
        float mu = S * invN;
        float var = Q * invN - mu * mu;
        float sc = g4[tid] * rsqrtf(var + BN_EPS);
        sscl[tid] = sc;
        sshl[tid] = be4[tid] - mu * sc;
    }
    __syncthreads();
    if (tid < OUTD) {
        float dv = 0.f;
        for (int k = 0; k < DIM; ++k) dv = fmaf(sshl[k], Wl[k * OUTD + tid], dv);
        dvec[tid] = dv;
    }
    __syncthreads();
    int t = blockIdx.x * 256 + tid;
    int g = t >> 7;
    int o = t & (OUTD - 1);
    float acc = bfc[o] + cntg[g] * dvec[o];
    const float* pr = praw + (long)g * DIM;
#pragma unroll
    for (int k = 0; k < DIM; ++k)
        acc = fmaf(sscl[k] * pr[k], Wl[k * OUTD + o], acc);
    out[t] = fmaxf(acc, 0.f);
}

extern "C" void kernel_launch(void* const* d_in, const int* in_sizes, int n_in,
                              void* d_out, int out_size, void* d_ws, size_t ws_size,
                              hipStream_t stream) {
    const float* x      = (const float*)d_in[0];
    const int*   ei     = (const int*)  d_in[1];
    const int*   batch  = (const int*)  d_in[2];
    const float* W1_0   = (const float*)d_in[3];
    const float* W1_rest= (const float*)d_in[4];
    const float* b1     = (const float*)d_in[5];
    const float* W2     = (const float*)d_in[6];
    const float* b2     = (const float*)d_in[7];
    const float* gamma  = (const float*)d_in[8];
    const float* beta   = (const float*)d_in[9];
    const float* Wfc    = (const float*)d_in[10];
    const float* bfc    = (const float*)d_in[11];
    float* out = (float*)d_out;

    int* wsi = (int*)d_ws;
    const size_t nf = (size_t)N_NODES * DIM;                   // 3.2M elems
    const size_t BD = (size_t)NBUK * STRIDE;                   // 1,801,728 ints
    int*   bdata  = wsi;                 // also edge_new after cfill2
    int*   edge_new = bdata;
    unsigned short* zfpA = (unsigned short*)(wsi + BD);        // 6.4 MB
    unsigned short* zfpB = zfpA + nf;                          // 6.4 MB
    int*   edge_src = (int*)(zfpB + nf);                       // 1.6M ints
    int2*  pinfo  = (int2*)(edge_src + N_EDGES);               // 100K int2
    int*   obeg   = (int*)(pinfo + N_NODES);                   // 100K
    int*   offsB  = obeg + N_NODES;                            // 391*257
    int*   perm   = offsB + NBUK * OSTR;                       // 100,000
    int*   bcnt   = perm + N_NODES;                            // 391
    int*   gcursor= bcnt + NBUK;                               // 1
    int*   ecursor= gcursor + 1;                               // 1
    float* praw   = (float*)(ecursor + 1);                     // 65,536
    float* cntg   = praw + (size_t)N_GRAPHS * DIM;             // 2,048
    float* partial= cntg + N_GRAPHS;                           // 5*1024

    hipMemsetAsync(praw, 0,
        ((size_t)N_GRAPHS * DIM + N_GRAPHS + NLAYERS * PSTRIDE) * sizeof(float),
        stream);
    hipMemsetAsync(bcnt, 0, (size_t)(NBUK + 2) * sizeof(int), stream);

    const int grpBlocks = (N_NODES * 8) / 256;                 // 3125

    // prep: bucket fill (391 blocks) || gemm1 (3125 blocks)
    prep_kernel<<<NBLK + grpBlocks, 256, 0, stream>>>(
        ei, bcnt, bdata, x, W1_0, zfpA);
    cfill2_kernel<<<NBUK, 256, 0, stream>>>(
        bcnt, bdata, edge_src, offsB, gcursor);
    wsort_kernel<<<NWIN, 256, 0, stream>>>(offsB, perm, pinfo, obeg, ecursor);
    ecopy_kernel<<<(N_NODES + 255) / 256, 256, 0, stream>>>(
        pinfo, obeg, edge_src, edge_new);

    // layer 0: gather y0, no matmul fold
    layer_kernel<false><<<NB2, 256, 0, stream>>>(
        perm, pinfo, edge_new, zfpA, nullptr, nullptr, nullptr, nullptr,
        b1, W2, b2, zfpB, partial);

    // layers 1..4: prologue folds prev BN into W1
    const unsigned short* zi = zfpB;
    unsigned short* zo = zfpA;
    for (int i = 1; i < NLAYERS; ++i) {
        layer_kernel<true><<<NB2, 256, 0, stream>>>(
            perm, pinfo, edge_new, zi,
            W1_rest + (size_t)(i - 1) * DIM * DIM,
            partial + (size_t)(i - 1) * PSTRIDE,
            gamma + (i - 1) * DIM, beta + (i - 1) * DIM,
            b1 + i * DIM, W2 + (size_t)i * DIM * DIM, b2 + i * DIM,
            zo, partial + (size_t)i * PSTRIDE);
        const unsigned short* tmp = zi; zi = zo; zo = (unsigned short*)tmp;
    }

    // pool raw sums + counts, then fc applies layer-4 BN
    pool_kernel<<<N_NODES / 32, 256, 0, stream>>>(zi, batch, praw, cntg);
    fc_kernel<<<(N_GRAPHS * OUTD) / 256, 256, 0, stream>>>(
        praw, cntg, partial + (size_t)(NLAYERS - 1) * PSTRIDE,
        gamma + (NLAYERS - 1) * DIM, beta + (NLAYERS - 1) * DIM,
        Wfc, bfc, out);
}

// Round 22
// 274.431 us; speedup vs baseline: 1.1917x; 1.1917x over previous
//
#include <hip/hip_runtime.h>
#include <hip/hip_fp16.h>

#define N_NODES 100000
#define N_EDGES 1600000
#define N_GRAPHS 2048
#define NFEAT 78
#define DIM 32
#define NLAYERS 5
#define OUTD 128
#define BN_EPS 1e-5f
#define NPB 32                       // nodes per tile
#define NT (N_NODES / NPB)           // 3125 tiles
#define NB2 ((NT + 1) / 2)           // 1563 layer blocks (2 tiles each, paired)
#define NBUK 391                     // coarse buckets (256 nodes each)
#define BNODES 256                   // nodes per bucket
#define STRIDE 4608                  // slab per bucket (mean 4092, +8 sigma)
#define EPB 4096                     // edges per bfill block
#define NBLK ((N_EDGES + EPB - 1) / EPB)      // 391
#define NSLOT 16                     // partial-stats slots
#define PSTRIDE (NSLOT * 2 * DIM)    // 1024 floats
#define OSTR (BNODES + 1)            // per-bucket offs stride (257)
#define WIN 4096                     // degree-sort window (nodes)
#define NWIN ((N_NODES + WIN - 1) / WIN)      // 25

// fp16 helpers
__device__ __forceinline__ float2 up2(unsigned u) {
    __half2 h = *reinterpret_cast<__half2*>(&u);
    return __half22float2(h);
}
__device__ __forceinline__ unsigned pk2(float a, float b) {
    __half2 h = __floats2half2_rn(a, b);
    return *reinterpret_cast<unsigned*>(&h);
}

// ---- prep: blocks [0,NBLK) bucket fill; rest gemm1 (x @ W1_0 -> fp16) ----
__global__ __launch_bounds__(256) void prep_kernel(
    const int* __restrict__ ei, int* __restrict__ bcnt, int* __restrict__ bdata,
    const float* __restrict__ x, const float* __restrict__ W1_0,
    unsigned short* __restrict__ y)
{
    __shared__ int cur[NBUK];
    __shared__ int gbl[NBUK];
    __shared__ float Wl[NFEAT * DIM];   // 9.75 KB
    int tid = threadIdx.x;

    if (blockIdx.x < NBLK) {
        int base = blockIdx.x * EPB;
        for (int i = tid; i < NBUK; i += 256) cur[i] = 0;
        __syncthreads();

        int ew[16], eb[16];
        const int4* s4 = (const int4*)ei;
        const int4* d4 = (const int4*)(ei + N_EDGES);
#pragma unroll
        for (int c = 0; c < 4; ++c) {
            int eidx = base + c * 1024 + tid * 4;
            if (eidx < N_EDGES) {
                int4 sv = s4[eidx >> 2];
                int4 dv = d4[eidx >> 2];
                ew[c*4+0] = sv.x | ((dv.x & 255) << 17); eb[c*4+0] = dv.x >> 8;
                ew[c*4+1] = sv.y | ((dv.y & 255) << 17); eb[c*4+1] = dv.y >> 8;
                ew[c*4+2] = sv.z | ((dv.z & 255) << 17); eb[c*4+2] = dv.z >> 8;
                ew[c*4+3] = sv.w | ((dv.w & 255) << 17); eb[c*4+3] = dv.w >> 8;
            } else {
                eb[c*4+0] = eb[c*4+1] = eb[c*4+2] = eb[c*4+3] = -1;
                ew[c*4+0] = ew[c*4+1] = ew[c*4+2] = ew[c*4+3] = 0;
            }
        }
        int slot[16];
#pragma unroll
        for (int k = 0; k < 16; ++k)
            slot[k] = (eb[k] >= 0) ? atomicAdd(&cur[eb[k]], 1) : 0;
        __syncthreads();
        for (int b = tid; b < NBUK; b += 256) {
            int c = cur[b];
            gbl[b] = (c > 0) ? atomicAdd(&bcnt[b], c) : 0;
        }
        __syncthreads();
#pragma unroll
        for (int k = 0; k < 16; ++k) {
            int b = eb[k];
            if (b >= 0) {
                int pos = gbl[b] + slot[k];
                if (pos < STRIDE) bdata[b * STRIDE + pos] = ew[k];
            }
        }
    } else {
        for (int i = tid; i < NFEAT * DIM; i += 256) Wl[i] = W1_0[i];
        __syncthreads();
        int t = (blockIdx.x - NBLK) * 256 + tid;
        int row = t >> 3;
        int c0 = (t & 7) * 4;
        float a0 = 0.f, a1 = 0.f, a2 = 0.f, a3 = 0.f;
        const float* hr = x + (long)row * NFEAT;
        for (int k = 0; k < NFEAT; ++k) {
            float xv = hr[k];
            a0 = fmaf(xv, Wl[k * DIM + c0 + 0], a0);
            a1 = fmaf(xv, Wl[k * DIM + c0 + 1], a1);
            a2 = fmaf(xv, Wl[k * DIM + c0 + 2], a2);
            a3 = fmaf(xv, Wl[k * DIM + c0 + 3], a3);
        }
        ((uint2*)y)[(long)row * 8 + (t & 7)] = make_uint2(pk2(a0, a1), pk2(a2, a3));
    }
}

// ---- cfill2: per-bucket LDS counting sort -> flat CSR ----
__global__ __launch_bounds__(256) void cfill2_kernel(
    const int* __restrict__ bcnt, const int* __restrict__ bdata,
    int* __restrict__ edge_src, int* __restrict__ offsB,
    int* __restrict__ gcursor)
{
    __shared__ int sorted[STRIDE];          // 18.4 KB
    __shared__ int cnt[BNODES], off[BNODES], cur[BNODES];
    __shared__ int gbS;
    int b = blockIdx.x, tid = threadIdx.x;
    int n = min(bcnt[b], STRIDE);
    const int* slab = bdata + (long)b * STRIDE;

    if (tid == 0) gbS = atomicAdd(gcursor, n);
    if (tid < BNODES) cnt[tid] = 0;
    __syncthreads();
    int gb = gbS;
    for (int i = tid; i < n; i += 256)
        atomicAdd(&cnt[slab[i] >> 17], 1);
    __syncthreads();
    int t = tid;
    if (t < BNODES) off[t] = cnt[t];
    __syncthreads();
    for (int o = 1; o < BNODES; o <<= 1) {
        int a = (t >= o && t < BNODES) ? off[t - o] : 0;
        __syncthreads();
        if (t < BNODES) off[t] += a;
        __syncthreads();
    }
    if (t < BNODES) {
        int excl = off[t] - cnt[t];
        off[t] = excl;
        cur[t] = excl;
        offsB[b * OSTR + t] = gb + excl;
    }
    if (tid == 0) offsB[b * OSTR + BNODES] = gb + n;
    __syncthreads();
    for (int i = tid; i < n; i += 256) {
        int w = slab[i];
        int pos = atomicAdd(&cur[w >> 17], 1);
        sorted[pos] = w & 0x1FFFF;
    }
    __syncthreads();
    for (int i = tid; i < n; i += 256)
        edge_src[gb + i] = sorted[i];
}

// ---- wsort: per-window (4096 nodes) LDS counting sort by degree bin ----
__global__ __launch_bounds__(256) void wsort_kernel(
    const int* __restrict__ offsB, int* __restrict__ perm)
{
    __shared__ int hist[64], cur[64];
    int tid = threadIdx.x;
    int wbase = blockIdx.x * WIN;
    int wn = min(WIN, N_NODES - wbase);
    if (tid < 64) hist[tid] = 0;
    __syncthreads();
    int bins[WIN / 256];
#pragma unroll
    for (int k = 0; k < WIN / 256; ++k) {
        int i = k * 256 + tid;
        int bin = -1;
        if (i < wn) {
            int node = wbase + i;
            int ob = (node >> 8) * OSTR + (node & 255);
            bin = min(offsB[ob + 1] - offsB[ob], 63);
            atomicAdd(&hist[bin], 1);
        }
        bins[k] = bin;
    }
    __syncthreads();
    if (tid < 64) {
        int v = hist[tid];
        int s = v;
        for (int off = 1; off < 64; off <<= 1) {
            int a = __shfl_up(s, off, 64);
            if ((tid & 63) >= off) s += a;
        }
        cur[tid] = s - v;
    }
    __syncthreads();
#pragma unroll
    for (int k = 0; k < WIN / 256; ++k) {
        int bin = bins[k];
        if (bin >= 0) {
            int node = wbase + k * 256 + tid;
            int p = atomicAdd(&cur[bin], 1);
            perm[wbase + p] = node;
        }
    }
}

// ---- fused layer: 2 reflected-pair tiles per block (deg-balanced, single
//      resident pass).  Prologue (MM): reduce prev partial -> BN, fold W1. ----
template<bool MM>
__global__ __launch_bounds__(256) void layer_kernel(
    const int* __restrict__ perm,
    const int* __restrict__ offsB, const int* __restrict__ edge_src,
    const unsigned short* __restrict__ zin,
    const float* __restrict__ W1g,          // unscaled W1 (MM only)
    const float* __restrict__ partial_prev, // prev stats (MM only)
    const float* __restrict__ gprev, const float* __restrict__ bprev,
    const float* __restrict__ b1v,
    const float* __restrict__ W2, const float* __restrict__ b2v,
    unsigned short* __restrict__ zout, float* __restrict__ partial)
{
    __shared__ float W1l[DIM * DIM];       // 4 KB (MM only)
    __shared__ float W2l[DIM * DIM];       // 4 KB
    __shared__ float zs[NPB][36];          // 4.5 KB; also prologue scratch
    __shared__ float b1l[DIM], b2l[DIM], cl[DIM];
    __shared__ float sscl[DIM], sshl[DIM];
    __shared__ float psum[DIM], psq[DIM];

    int tid = threadIdx.x;
    float* red = &zs[0][0];

    for (int i = tid; i < DIM * DIM; i += 256) W2l[i] = W2[i];
    if (tid < DIM) {
        b1l[tid] = b1v[tid]; b2l[tid] = b2v[tid];
        psum[tid] = 0.f; psq[tid] = 0.f;
    }
    if (MM) {
        int c = tid & 63, chunk = tid >> 6;
        float a = 0.f;
        for (int p = chunk; p < NSLOT; p += 4) a += partial_prev[p * 64 + c];
        red[tid] = a;
        __syncthreads();
        if (tid < 64) red[tid] = red[tid] + red[tid+64] + red[tid+128] + red[tid+192];
        __syncthreads();
        if (tid < DIM) {
            const float invN = 1.0f / (float)N_NODES;
            float S = red[tid], Q = red[tid + DIM];
            float mu = S * invN;
            float var = Q * invN - mu * mu;
            float sc = gprev[tid] * rsqrtf(var + BN_EPS);
            sscl[tid] = sc;
            sshl[tid] = bprev[tid] - mu * sc;
        }
        __syncthreads();
        for (int i = tid; i < DIM * DIM; i += 256) W1l[i] = sscl[i >> 5] * W1g[i];
        if (tid < DIM) {
            float cv = 0.f;
            for (int k = 0; k < DIM; ++k) cv = fmaf(sshl[k], W1g[k * DIM + tid], cv);
            cl[tid] = cv;
        }
    }
    __syncthreads();   // weights ready; zs scratch free

    int ln = tid >> 3, p = tid & 7;
    int c0 = p * 4;
    const uint2* zb = (const uint2*)zin;

    // two reflected-pair tiles: (b) ascending + (NT-1-b) descending degree
#pragma unroll 1
    for (int tt = 0; tt < 2; ++tt) {
        int tile = tt ? (NT - 1 - (int)blockIdx.x) : (int)blockIdx.x;
        if (tt && tile <= (int)blockIdx.x) break;   // middle tile: once only

        int node = perm[tile * NPB + ln];
        int ob = (node >> 8) * OSTR + (node & 255);
        int beg = offsB[ob], end = offsB[ob + 1];
        int deg = end - beg;

        // phase 1: gather (self + in-neighbors), unroll x8
        uint2 sv = zb[(long)node * 8 + p];
        float2 f;
        f = up2(sv.x); float a0 = f.x, a1 = f.y;
        f = up2(sv.y); float a2 = f.x, a3 = f.y;
        int e = beg;
        for (; e + 8 <= end; e += 8) {
            uint2 v0 = zb[(long)edge_src[e + 0] * 8 + p];
            uint2 v1 = zb[(long)edge_src[e + 1] * 8 + p];
            uint2 v2 = zb[(long)edge_src[e + 2] * 8 + p];
            uint2 v3 = zb[(long)edge_src[e + 3] * 8 + p];
            uint2 v4 = zb[(long)edge_src[e + 4] * 8 + p];
            uint2 v5 = zb[(long)edge_src[e + 5] * 8 + p];
            uint2 v6 = zb[(long)edge_src[e + 6] * 8 + p];
            uint2 v7 = zb[(long)edge_src[e + 7] * 8 + p];
            f = up2(v0.x); a0 += f.x; a1 += f.y;  f = up2(v0.y); a2 += f.x; a3 += f.y;
            f = up2(v1.x); a0 += f.x; a1 += f.y;  f = up2(v1.y); a2 += f.x; a3 += f.y;
            f = up2(v2.x); a0 += f.x; a1 += f.y;  f = up2(v2.y); a2 += f.x; a3 += f.y;
            f = up2(v3.x); a0 += f.x; a1 += f.y;  f = up2(v3.y); a2 += f.x; a3 += f.y;
            f = up2(v4.x); a0 += f.x; a1 += f.y;  f = up2(v4.y); a2 += f.x; a3 += f.y;
            f = up2(v5.x); a0 += f.x; a1 += f.y;  f = up2(v5.y); a2 += f.x; a3 += f.y;
            f = up2(v6.x); a0 += f.x; a1 += f.y;  f = up2(v6.y); a2 += f.x; a3 += f.y;
            f = up2(v7.x); a0 += f.x; a1 += f.y;  f = up2(v7.y); a2 += f.x; a3 += f.y;
        }
        for (; e < end; ++e) {
            uint2 v = zb[(long)edge_src[e] * 8 + p];
            f = up2(v.x); a0 += f.x; a1 += f.y;
            f = up2(v.y); a2 += f.x; a3 += f.y;
        }
        *(float4*)&zs[ln][c0] = make_float4(a0, a1, a2, a3);
        // no barrier: zs row is wave-private (same-wave DS order)

        // phase 2: s = zsum@W1' + (deg+1)*c + b1 (or zsum + b1), relu; in-place
        float t4[4];
        if (MM) {
            t4[0] = t4[1] = t4[2] = t4[3] = 0.f;
#pragma unroll
            for (int k = 0; k < DIM; ++k) {
                float zk = zs[ln][k];
                t4[0] = fmaf(zk, W1l[k * DIM + c0 + 0], t4[0]);
                t4[1] = fmaf(zk, W1l[k * DIM + c0 + 1], t4[1]);
                t4[2] = fmaf(zk, W1l[k * DIM + c0 + 2], t4[2]);
                t4[3] = fmaf(zk, W1l[k * DIM + c0 + 3], t4[3]);
            }
            float dp1 = (float)(deg + 1);
#pragma unroll
            for (int j = 0; j < 4; ++j)
                t4[j] = fmaxf(fmaf(dp1, cl[c0 + j], t4[j]) + b1l[c0 + j], 0.f);
        } else {
            t4[0] = fmaxf(a0 + b1l[c0 + 0], 0.f);
            t4[1] = fmaxf(a1 + b1l[c0 + 1], 0.f);
            t4[2] = fmaxf(a2 + b1l[c0 + 2], 0.f);
            t4[3] = fmaxf(a3 + b1l[c0 + 3], 0.f);
        }
        *(float4*)&zs[ln][c0] = make_float4(t4[0], t4[1], t4[2], t4[3]);
        // lockstep wave: all k-loop reads above complete before this store

        // phase 3: z = relu(s@W2 + b2), fp16 write + stats
        float zv[4] = { b2l[c0 + 0], b2l[c0 + 1], b2l[c0 + 2], b2l[c0 + 3] };
#pragma unroll
        for (int k = 0; k < DIM; ++k) {
            float sk = zs[ln][k];
            zv[0] = fmaf(sk, W2l[k * DIM + c0 + 0], zv[0]);
            zv[1] = fmaf(sk, W2l[k * DIM + c0 + 1], zv[1]);
            zv[2] = fmaf(sk, W2l[k * DIM + c0 + 2], zv[2]);
            zv[3] = fmaf(sk, W2l[k * DIM + c0 + 3], zv[3]);
        }
#pragma unroll
        for (int j = 0; j < 4; ++j) zv[j] = fmaxf(zv[j], 0.f);
        ((uint2*)zout)[(long)node * 8 + p] =
            make_uint2(pk2(zv[0], zv[1]), pk2(zv[2], zv[3]));

        // BN partial stats: wave-reduce, accumulate in LDS
        float sq[4];
#pragma unroll
        for (int j = 0; j < 4; ++j) sq[j] = zv[j] * zv[j];
#pragma unroll
        for (int off = 8; off < 64; off <<= 1) {
#pragma unroll
            for (int j = 0; j < 4; ++j) {
                zv[j] += __shfl_xor(zv[j], off, 64);
                sq[j] += __shfl_xor(sq[j], off, 64);
            }
        }
        if ((tid & 63) < 8) {
#pragma unroll
            for (int j = 0; j < 4; ++j) {
                atomicAdd(&psum[c0 + j], zv[j]);
                atomicAdd(&psq[c0 + j], sq[j]);
            }
        }
    }

    __syncthreads();
    if (tid < 2 * DIM) {
        float v = (tid < DIM) ? psum[tid] : psq[tid - DIM];
        atomicAdd(&partial[(blockIdx.x & (NSLOT - 1)) * 2 * DIM + tid], v);
    }
}

// ------- pool: RAW sums + per-graph node counts (no BN dependency) -------
__global__ __launch_bounds__(256) void pool_kernel(
    const unsigned short* __restrict__ z, const int* __restrict__ batch,
    float* __restrict__ praw, float* __restrict__ cntg)
{
    __shared__ float acc[32][32];
    __shared__ float cntL[32];
    __shared__ int slot[32];
    __shared__ int segg[32];
    __shared__ int nsegS;
    int tid = threadIdx.x;
    for (int i = tid; i < 1024; i += 256) ((float*)acc)[i] = 0.f;
    if (tid < 32) cntL[tid] = 0.f;
    int nodeBase = blockIdx.x * 32;
    if (tid < 32) {
        int nd = nodeBase + tid;
        int gv = batch[nd];
        int flag = (tid == 0) ? 1 : (gv != batch[nd - 1]);
        unsigned long long m = __ballot(flag);
        int s = __popcll(m & ((2ull << tid) - 1ull)) - 1;
        slot[tid] = s;
        if (flag) segg[s] = gv;
        if (tid == 0) nsegS = __popcll(m);
    }
    __syncthreads();

    int ln = tid >> 3;
    int p = tid & 7;
    long node = nodeBase + ln;
    uint2 u = ((const uint2*)z)[node * 8 + p];
    int c = p * 4;
    float2 f01 = up2(u.x), f23 = up2(u.y);
    int s = slot[ln];
    atomicAdd(&acc[s][c+0], f01.x);
    atomicAdd(&acc[s][c+1], f01.y);
    atomicAdd(&acc[s][c+2], f23.x);
    atomicAdd(&acc[s][c+3], f23.y);
    if (p == 0) atomicAdd(&cntL[s], 1.f);
    __syncthreads();

    int total = nsegS * 32;
    for (int i = tid; i < total; i += 256) {
        int r = i >> 5, dd = i & 31;
        float val = acc[r][dd];
        if (val != 0.f) atomicAdd(&praw[(long)segg[r] * DIM + dd], val);
    }
    if (tid < nsegS) atomicAdd(&cntg[segg[tid]], cntL[tid]);
}

// ---- fc: prologue computes layer-4 BN from partial4, then
//      out = relu(bfc + cnt*(shl@Wfc) + (scl.*praw)@Wfc) ----
__global__ __launch_bounds__(256) void fc_kernel(
    const float* __restrict__ praw, const float* __restrict__ cntg,
    const float* __restrict__ partial4,
    const float* __restrict__ g4, const float* __restrict__ be4,
    const float* __restrict__ Wfc, const float* __restrict__ bfc,
    float* __restrict__ out)
{
    __shared__ float Wl[DIM * OUTD];   // 16 KB
    __shared__ float red[256];
    __shared__ float sscl[DIM], sshl[DIM], dvec[OUTD];
    int tid = threadIdx.x;
    for (int i = tid; i < DIM * OUTD; i += 256) Wl[i] = Wfc[i];
    {
        int c = tid & 63, chunk = tid >> 6;
        float a = 0.f;
        for (int p = chunk; p < NSLOT; p += 4) a += partial4[p * 64 + c];
        red[tid] = a;
    }
    __syncthreads();
    if (tid < 64) red[tid] = red[tid] + red[tid+64] + red[tid+128] + red[tid+192];
    __syncthreads();
    if (tid < DIM) {
        const float invN = 1.0f / (float)N_NODES;
        float S = red[tid], Q = red[tid + DIM];
        float mu = S * invN;
        float var = Q * invN - mu * mu;
        float sc = g4[tid] * rsqrtf(var + BN_EPS);
        sscl[tid] = sc;
        sshl[tid] = be4[tid] - mu * sc;
    }
    __syncthreads();
    if (tid < OUTD) {
        float dv = 0.f;
        for (int k = 0; k < DIM; ++k) dv = fmaf(sshl[k], Wl[k * OUTD + tid], dv);
        dvec[tid] = dv;
    }
    __syncthreads();
    int t = blockIdx.x * 256 + tid;
    int g = t >> 7;
    int o = t & (OUTD - 1);
    float acc = bfc[o] + cntg[g] * dvec[o];
    const float* pr = praw + (long)g * DIM;
#pragma unroll
    for (int k = 0; k < DIM; ++k)
        acc = fmaf(sscl[k] * pr[k], Wl[k * OUTD + o], acc);
    out[t] = fmaxf(acc, 0.f);
}

extern "C" void kernel_launch(void* const* d_in, const int* in_sizes, int n_in,
                              void* d_out, int out_size, void* d_ws, size_t ws_size,
                              hipStream_t stream) {
    const float* x      = (const float*)d_in[0];
    const int*   ei     = (const int*)  d_in[1];
    const int*   batch  = (const int*)  d_in[2];
    const float* W1_0   = (const float*)d_in[3];
    const float* W1_rest= (const float*)d_in[4];
    const float* b1     = (const float*)d_in[5];
    const float* W2     = (const float*)d_in[6];
    const float* b2     = (const float*)d_in[7];
    const float* gamma  = (const float*)d_in[8];
    const float* beta   = (const float*)d_in[9];
    const float* Wfc    = (const float*)d_in[10];
    const float* bfc    = (const float*)d_in[11];
    float* out = (float*)d_out;

    int* wsi = (int*)d_ws;
    const size_t nf = (size_t)N_NODES * DIM;                   // 3.2M elems
    const size_t BD = (size_t)NBUK * STRIDE;                   // 1,801,728 ints
    int*   bdata  = wsi;
    unsigned short* zfpA = (unsigned short*)(wsi + BD);        // 6.4 MB
    unsigned short* zfpB = zfpA + nf;                          // 6.4 MB
    int*   edge_src = (int*)(zfpB + nf);                       // 1.6M ints
    int*   offsB  = edge_src + N_EDGES;                        // 391*257
    int*   perm   = offsB + NBUK * OSTR;                       // 100,000
    int*   bcnt   = perm + N_NODES;                            // 391
    int*   gcursor= bcnt + NBUK;                               // 1
    float* praw   = (float*)(gcursor + 1);                     // 65,536
    float* cntg   = praw + (size_t)N_GRAPHS * DIM;             // 2,048
    float* partial= cntg + N_GRAPHS;                           // 5*1024

    hipMemsetAsync(praw, 0,
        ((size_t)N_GRAPHS * DIM + N_GRAPHS + NLAYERS * PSTRIDE) * sizeof(float),
        stream);
    hipMemsetAsync(bcnt, 0, (size_t)(NBUK + 1) * sizeof(int), stream);

    const int grpBlocks = (N_NODES * 8) / 256;                 // 3125

    // prep: bucket fill (391 blocks) || gemm1 (3125 blocks)
    prep_kernel<<<NBLK + grpBlocks, 256, 0, stream>>>(
        ei, bcnt, bdata, x, W1_0, zfpA);
    cfill2_kernel<<<NBUK, 256, 0, stream>>>(
        bcnt, bdata, edge_src, offsB, gcursor);
    wsort_kernel<<<NWIN, 256, 0, stream>>>(offsB, perm);

    // layer 0: gather y0, no matmul fold
    layer_kernel<false><<<NB2, 256, 0, stream>>>(
        perm, offsB, edge_src, zfpA, nullptr, nullptr, nullptr, nullptr,
        b1, W2, b2, zfpB, partial);

    // layers 1..4: prologue folds prev BN into W1
    const unsigned short* zi = zfpB;
    unsigned short* zo = zfpA;
    for (int i = 1; i < NLAYERS; ++i) {
        layer_kernel<true><<<NB2, 256, 0, stream>>>(
            perm, offsB, edge_src, zi,
            W1_rest + (size_t)(i - 1) * DIM * DIM,
            partial + (size_t)(i - 1) * PSTRIDE,
            gamma + (i - 1) * DIM, beta + (i - 1) * DIM,
            b1 + i * DIM, W2 + (size_t)i * DIM * DIM, b2 + i * DIM,
            zo, partial + (size_t)i * PSTRIDE);
        const unsigned short* tmp = zi; zi = zo; zo = (unsigned short*)tmp;
    }

    // pool raw sums + counts, then fc applies layer-4 BN
    pool_kernel<<<N_NODES / 32, 256, 0, stream>>>(zi, batch, praw, cntg);
    fc_kernel<<<(N_GRAPHS * OUTD) / 256, 256, 0, stream>>>(
        praw, cntg, partial + (size_t)(NLAYERS - 1) * PSTRIDE,
        gamma + (NLAYERS - 1) * DIM, beta + (NLAYERS - 1) * DIM,
        Wfc, bfc, out);
}